// Round 4
// baseline (1008.618 us; speedup 1.0000x reference)
//
#include <hip/hip_runtime.h>
#include <math.h>

#define NN 4096
#define CC 256
#define HH 64
#define BT 16
#define KCC 100
#define NHH 8
#define HDD 32
#define C4 1024

typedef unsigned short bf16_t;
typedef short s16x8 __attribute__((ext_vector_type(8)));
typedef float f32x4 __attribute__((ext_vector_type(4)));
typedef float f32x16 __attribute__((ext_vector_type(16)));

__device__ __forceinline__ float bf2f(bf16_t h) {
  return __uint_as_float(((unsigned)h) << 16);
}
__device__ __forceinline__ bf16_t f2bf(float f) {
  unsigned u = __float_as_uint(f);
  return (bf16_t)((u + 0x7FFFu + ((u >> 16) & 1u)) >> 16);
}

__device__ __forceinline__ float gelu_f(float x) {
  return 0.5f * x * (1.0f + erff(x * 0.7071067811865475f));
}

// async global->LDS, 16 B per lane; lds dest = wave-uniform base + lane*16
__device__ __forceinline__ void g2l16(const void* g, void* l) {
  __builtin_amdgcn_global_load_lds((const __attribute__((address_space(1))) void*)g,
                                   (__attribute__((address_space(3))) void*)l, 16, 0, 0);
}

__device__ __forceinline__ float block_sum256(float v) {
  __shared__ float sh[4];
#pragma unroll
  for (int off = 32; off; off >>= 1) v += __shfl_xor(v, off, 64);
  __syncthreads();
  if ((threadIdx.x & 63) == 0) sh[threadIdx.x >> 6] = v;
  __syncthreads();
  return sh[0] + sh[1] + sh[2] + sh[3];
}

__device__ __forceinline__ const float* xt_base(const float* x, const float* mem, int bt) {
  int b = bt >> 2, tt = bt & 3;
  return (tt < 3) ? (mem + (size_t)(b * 3 + tt) * NN * CC)
                  : (x + (size_t)b * NN * CC);
}

// fused prologue: [0,16384) build xtb; [16384,19520) transpose conv1_w -> wtb;
// [19520,22436) convert 6 weight mats to bf16 pack wbz.
__global__ __launch_bounds__(256) void prologue(const float* __restrict__ x,
                                                const float* __restrict__ mem,
                                                bf16_t* __restrict__ xtb,
                                                const float* __restrict__ w1,
                                                bf16_t* __restrict__ wtb,
                                                const float* __restrict__ c2w,
                                                const float* __restrict__ c3w,
                                                const float* __restrict__ qw,
                                                const float* __restrict__ pw,
                                                const float* __restrict__ f1w,
                                                const float* __restrict__ f2w,
                                                bf16_t* __restrict__ wbz) {
  int bid = blockIdx.x;
  int tid = threadIdx.x;
  if (bid < 16384) {
    int i = bid * 256 + tid;
    int c4 = i & 63;
    int n = (i >> 6) & 4095;
    int bt = i >> 18;
    const float* src = xt_base(x, mem, bt) + (size_t)n * CC + c4 * 4;
    float4 v = *(const float4*)src;
    ushort4 o;
    o.x = f2bf(v.x); o.y = f2bf(v.y); o.z = f2bf(v.z); o.w = f2bf(v.w);
    *(ushort4*)(xtb + (size_t)i * 4) = o;
  } else if (bid < 19520) {
    int i = (bid - 16384) * 256 + tid;  // < 802816 exactly
    int cj = i & 7;
    int t = i >> 3;
    int co = t & 63; t >>= 6;
    int oc = t & 3; t >>= 2;
    int kx = t % 7; t /= 7;
    int cq = t & 3; t >>= 2;
    int cg = t & 7;
    int ky = t >> 3;
    int ci = cg * 32 + oc * 8 + cj;
    int cog = cq * 64 + co;
    wtb[i] = f2bf(w1[((size_t)(cog * CC + ci) * 7 + ky) * 7 + kx]);
  } else {
    int j = (bid - 19520) * 256 + tid;  // < 746496 exactly
    float v;
    if (j < 65536) v = c2w[j];
    else if (j < 91136) v = c3w[j - 65536];
    else if (j < 156672) v = qw[j - 91136];
    else if (j < 222208) v = pw[j - 156672];
    else if (j < 484352) v = f1w[j - 222208];
    else v = f2w[j - 484352];
    wbz[j] = f2bf(v);
  }
}

// conv1 v8: v7 + sched_group_barrier 1:1 DS_READ:MFMA interleave.
// v7 post-mortem: dur fits LDS-time + MFMA-time SUM for all 3 variants ->
// pipes run serially (convoy: waves bunch reads then bunch MFMAs, all
// 16 waves/CU phase-align). Fix = compile-time interleave (T19) so each
// wave feeds both pipes simultaneously. Rotation (v7) already made kx+1
// reads independent of kx MFMAs; the ladder pins emission order.
__global__ __launch_bounds__(512, 2) void conv1_mfma(const bf16_t* __restrict__ xtb,
                                                     const bf16_t* __restrict__ wtb,
                                                     const float* __restrict__ bias,
                                                     bf16_t* __restrict__ h1) {
  int bid = blockIdx.x;
  int cq = bid & 3;            // W-slice phase, XCD-aligned
  int rem = bid >> 2;          // 0..127
  int bt = rem & 15;
  int rb = rem >> 4;           // 0..7 : 8-row band
  int r0 = rb * 8;
  int co0 = cq * 64;
  int tid = threadIdx.x;
  int wv = tid >> 6;           // 0..7
  int lane = tid & 63;
  int l31 = lane & 31;
  int h = lane >> 5;           // 0..1 : k-half
  __shared__ __align__(16) short As[14][4][70][8];    // 62,720 B
  __shared__ __align__(16) short Ws[2][7][4][64][8];  // 57,344 B
  {
    s16x8 z = {0, 0, 0, 0, 0, 0, 0, 0};
    for (int i = tid; i < 14 * 4 * 70; i += 512) *(s16x8*)((short*)As + i * 8) = z;
  }
  __syncthreads();
  f32x16 acc[2][2] = {};       // [mt][nt] 32x32 tiles
  const bf16_t* xb = xtb + (size_t)bt * (NN * CC);
  for (int cig = 0; cig < 8; ++cig) {
    int ci0 = cig * 32;
    // stage As: 14 rows x 4 ci-subgroups (halo rows/cols stay zero)
    for (int t = wv; t < 56; t += 8) {
      int rr = t >> 2, go = t & 3;
      int r = r0 - 3 + rr;
      if (r >= 0 && r < HH) {
        const bf16_t* gsrc = xb + ((size_t)(r * 64 + lane)) * CC + ci0 + go * 8;
        g2l16(gsrc, &As[rr][go][3][0]);
      }
    }
    // stage Ws buf0, ky=0
    {
      const bf16_t* wk = wtb + ((size_t)((0 * 8 + cig) * 4 + cq)) * (1792 * 8);
      for (int t = wv; t < 28; t += 8)
        g2l16(wk + (size_t)t * 512 + lane * 8, (short*)Ws[0] + t * 512);
    }
    __syncthreads();
    for (int ky = 0; ky < 7; ++ky) {
      int cur = ky & 1;
      if (ky < 6) {  // prefetch next ky's W taps into the other buffer
        const bf16_t* wk = wtb + ((size_t)(((ky + 1) * 8 + cig) * 4 + cq)) * (1792 * 8);
        for (int t = wv; t < 28; t += 8)
          g2l16(wk + (size_t)t * 512 + lane * 8, (short*)Ws[cur ^ 1] + t * 512);
      }
      // kx software pipeline: frag sets A/B by parity, fully unrolled.
      s16x8 fa[2][2][2], fb[2][2][2];  // [parity][mt|nt][ks]
#pragma unroll
      for (int mt = 0; mt < 2; ++mt)
#pragma unroll
        for (int ks = 0; ks < 2; ++ks) {
          fa[0][mt][ks] = *(const s16x8*)&As[wv + ky][ks * 2 + h][mt * 32 + l31 + 0][0];
          fb[0][mt][ks] = *(const s16x8*)&Ws[cur][0][ks * 2 + h][mt * 32 + l31][0];
        }
#pragma unroll
      for (int kx = 0; kx < 7; ++kx) {
        int p = kx & 1;
        if (kx < 6) {
          int np = p ^ 1;
#pragma unroll
          for (int mt = 0; mt < 2; ++mt)
#pragma unroll
            for (int ks = 0; ks < 2; ++ks) {
              fa[np][mt][ks] =
                  *(const s16x8*)&As[wv + ky][ks * 2 + h][mt * 32 + l31 + kx + 1][0];
              fb[np][mt][ks] =
                  *(const s16x8*)&Ws[cur][kx + 1][ks * 2 + h][mt * 32 + l31][0];
            }
        }
#pragma unroll
        for (int ks = 0; ks < 2; ++ks)
#pragma unroll
          for (int mt = 0; mt < 2; ++mt)
#pragma unroll
            for (int nt = 0; nt < 2; ++nt)
              acc[mt][nt] = __builtin_amdgcn_mfma_f32_32x32x16_bf16(
                  fa[p][mt][ks], fb[p][nt][ks], acc[mt][nt], 0, 0, 0);
        if (kx < 6) {
          // T19: pin 1 DS_READ : 1 MFMA emission for this region so both
          // pipes are fed concurrently (8 reads for kx+1, 8 MFMAs for kx).
#pragma unroll
          for (int i = 0; i < 8; ++i) {
            __builtin_amdgcn_sched_group_barrier(0x100, 1, 0);  // DS_READ
            __builtin_amdgcn_sched_group_barrier(0x008, 1, 0);  // MFMA
          }
        }
      }
      __syncthreads();  // drains vmcnt: next Ws buffer ready; readers done
    }
  }
  int row = r0 + wv;
  const size_t xbase = (size_t)bt * (NN * CC);
#pragma unroll
  for (int nt = 0; nt < 2; ++nt) {
    int co = co0 + nt * 32 + l31;
    float bs = bias[co];
#pragma unroll
    for (int mt = 0; mt < 2; ++mt) {
#pragma unroll
      for (int rg = 0; rg < 16; ++rg) {
        int px = mt * 32 + (rg & 3) + 8 * (rg >> 2) + 4 * h;
        float vv = acc[mt][nt][rg] + bs;
        h1[xbase + (size_t)(row * 64 + px) * CC + co] = f2bf(gelu_f(vv));
      }
    }
  }
}

// bf16 MFMA GEMM with optional z-slab batching (unchanged)
template <int GELU, int BIAS, int TOUT, int OBF>
__global__ __launch_bounds__(256) void gemm_mfma(const bf16_t* __restrict__ A,
                                                 const bf16_t* __restrict__ W,
                                                 const float* __restrict__ bias,
                                                 void* __restrict__ outp,
                                                 int M, int N, int K, int ldo,
                                                 size_t aStr, size_t oStr) {
  __shared__ short As[128][40];
  __shared__ short Bs[128][40];
  A += (size_t)blockIdx.z * aStr;
  size_t obase = (size_t)blockIdx.z * oStr;
  int tid = threadIdx.x;
  int n0 = blockIdx.x * 128, m0 = blockIdx.y * 128;
  int lane = tid & 63, wv = tid >> 6;
  int wm = wv & 1, wn = wv >> 1;
  int lm = lane & 15, g = lane >> 4;
  f32x4 acc[4][4] = {};
  int r1 = tid >> 2, kq = tid & 3;
  int r2 = r1 + 64;
  for (int k0 = 0; k0 < K; k0 += 32) {
    *(s16x8*)&As[r1][kq * 8] = *(const s16x8*)(A + (size_t)(m0 + r1) * K + k0 + kq * 8);
    *(s16x8*)&As[r2][kq * 8] = *(const s16x8*)(A + (size_t)(m0 + r2) * K + k0 + kq * 8);
    s16x8 z = {0, 0, 0, 0, 0, 0, 0, 0};
    s16x8 b1 = z, b2 = z;
    if (n0 + r1 < N) b1 = *(const s16x8*)(W + (size_t)(n0 + r1) * K + k0 + kq * 8);
    if (n0 + r2 < N) b2 = *(const s16x8*)(W + (size_t)(n0 + r2) * K + k0 + kq * 8);
    *(s16x8*)&Bs[r1][kq * 8] = b1;
    *(s16x8*)&Bs[r2][kq * 8] = b2;
    __syncthreads();
    s16x8 af[4], bf[4];
#pragma unroll
    for (int mt = 0; mt < 4; ++mt)
      af[mt] = *(const s16x8*)&As[wm * 64 + mt * 16 + lm][g * 8];
#pragma unroll
    for (int nt = 0; nt < 4; ++nt)
      bf[nt] = *(const s16x8*)&Bs[wn * 64 + nt * 16 + lm][g * 8];
#pragma unroll
    for (int mt = 0; mt < 4; ++mt)
#pragma unroll
      for (int nt = 0; nt < 4; ++nt)
        acc[mt][nt] = __builtin_amdgcn_mfma_f32_16x16x32_bf16(af[mt], bf[nt],
                                                              acc[mt][nt], 0, 0, 0);
    __syncthreads();
  }
#pragma unroll
  for (int nt = 0; nt < 4; ++nt) {
    int n = n0 + wn * 64 + nt * 16 + lm;
    if (n >= N) continue;
    float bs = BIAS ? bias[n] : 0.f;
#pragma unroll
    for (int mt = 0; mt < 4; ++mt) {
#pragma unroll
      for (int rg = 0; rg < 4; ++rg) {
        int m = m0 + wm * 64 + mt * 16 + g * 4 + rg;
        float v = acc[mt][nt][rg] + bs;
        if (GELU) v = gelu_f(v);
        size_t idx = obase + (TOUT ? ((size_t)n * ldo + m) : ((size_t)m * ldo + n));
        if (OBF)
          ((bf16_t*)outp)[idx] = f2bf(v);
        else
          ((float*)outp)[idx] = v;
      }
    }
  }
}

// fused k/v projections: z=0 -> k, z=1 -> v. M=400, N=256, K=256.
__global__ __launch_bounds__(256) void gemm_kv(const float* __restrict__ cin,
                                               const float* __restrict__ kw,
                                               const float* __restrict__ kbias,
                                               const float* __restrict__ vw,
                                               const float* __restrict__ vbias,
                                               float* __restrict__ kout,
                                               float* __restrict__ vout) {
  const float* Wm = blockIdx.z ? vw : kw;
  const float* bias = blockIdx.z ? vbias : kbias;
  float* outp = blockIdx.z ? vout : kout;
  const int M = 400, N = 256, K = 256;
  __shared__ float As[16][68];
  __shared__ float Ws[16][68];
  int tid = threadIdx.x;
  int n0 = blockIdx.x * 64, m0 = blockIdx.y * 64;
  int txn = tid & 15, tym = tid >> 4;
  int mi = tid >> 2, kq = (tid & 3) * 4;
  float acc[4][4] = {};
  for (int k0 = 0; k0 < K; k0 += 16) {
    float4 av = {0, 0, 0, 0}, wvv = {0, 0, 0, 0};
    if (m0 + mi < M) av = *(const float4*)&cin[(size_t)(m0 + mi) * K + k0 + kq];
    if (n0 + mi < N) wvv = *(const float4*)&Wm[(size_t)(n0 + mi) * K + k0 + kq];
    As[kq + 0][mi] = av.x; As[kq + 1][mi] = av.y; As[kq + 2][mi] = av.z; As[kq + 3][mi] = av.w;
    Ws[kq + 0][mi] = wvv.x; Ws[kq + 1][mi] = wvv.y; Ws[kq + 2][mi] = wvv.z; Ws[kq + 3][mi] = wvv.w;
    __syncthreads();
#pragma unroll
    for (int ki = 0; ki < 16; ++ki) {
      float4 a4 = *(const float4*)&As[ki][tym * 4];
      float4 w4 = *(const float4*)&Ws[ki][txn * 4];
      float am[4] = {a4.x, a4.y, a4.z, a4.w};
      float wn[4] = {w4.x, w4.y, w4.z, w4.w};
#pragma unroll
      for (int i = 0; i < 4; ++i)
#pragma unroll
        for (int j = 0; j < 4; ++j) acc[i][j] += am[i] * wn[j];
    }
    __syncthreads();
  }
#pragma unroll
  for (int i = 0; i < 4; ++i) {
    int m = m0 + tym * 4 + i;
    if (m >= M) continue;
#pragma unroll
    for (int j = 0; j < 4; ++j) {
      int n = n0 + txn * 4 + j;
      outp[(size_t)m * 256 + n] = acc[i][j] + bias[n];
    }
  }
}

// 1600 rows of 4096 bf16, softmax in place; thread owns 16 contiguous elems
__global__ __launch_bounds__(256) void softmax_rows(bf16_t* __restrict__ p) {
  __shared__ float sh[8];
  int tid = threadIdx.x;
  bf16_t* base = p + (size_t)blockIdx.x * NN + tid * 16;
  s16x8 a = *(const s16x8*)base;
  s16x8 b = *(const s16x8*)(base + 8);
  float vals[16];
#pragma unroll
  for (int j = 0; j < 8; ++j) {
    vals[j] = bf2f((bf16_t)a[j]);
    vals[8 + j] = bf2f((bf16_t)b[j]);
  }
  float mx = -1e30f;
#pragma unroll
  for (int j = 0; j < 16; ++j) mx = fmaxf(mx, vals[j]);
#pragma unroll
  for (int off = 32; off; off >>= 1) mx = fmaxf(mx, __shfl_xor(mx, off, 64));
  if ((tid & 63) == 0) sh[tid >> 6] = mx;
  __syncthreads();
  mx = fmaxf(fmaxf(sh[0], sh[1]), fmaxf(sh[2], sh[3]));
  float s = 0.f;
#pragma unroll
  for (int j = 0; j < 16; ++j) {
    vals[j] = expf(vals[j] - mx);
    s += vals[j];
  }
#pragma unroll
  for (int off = 32; off; off >>= 1) s += __shfl_xor(s, off, 64);
  if ((tid & 63) == 0) sh[4 + (tid >> 6)] = s;
  __syncthreads();
  s = sh[4] + sh[5] + sh[6] + sh[7];
  float inv = 1.f / s;
  s16x8 oa, ob;
#pragma unroll
  for (int j = 0; j < 8; ++j) {
    oa[j] = (short)f2bf(vals[j] * inv);
    ob[j] = (short)f2bf(vals[8 + j] * inv);
  }
  *(s16x8*)base = oa;
  *(s16x8*)(base + 8) = ob;
}

// center via MFMA split-K (8 chunks of 512): partial[nc][bt][kc][c].
__global__ __launch_bounds__(256) void center_mfma(const bf16_t* __restrict__ soft,
                                                   const bf16_t* __restrict__ xtb,
                                                   float* __restrict__ partial) {
  int c0 = blockIdx.x * 128;
  int bt = blockIdx.y;
  int nc = blockIdx.z;
  int tid = threadIdx.x;
  int lane = tid & 63, wv = tid >> 6;
  int wm = wv & 1, wn = wv >> 1;
  int lm = lane & 15, g = lane >> 4;
  __shared__ short As[128][40];
  __shared__ short Bs[128][40];
  f32x4 acc[4][4] = {};
  int r1 = tid >> 2, kq = tid & 3;
  int r2 = r1 + 64;
  int bk = tid & 31, bc = (tid >> 5) * 16;
  const bf16_t* sb = soft + (size_t)bt * NN + (size_t)nc * 512;
  const bf16_t* xb = xtb + ((size_t)bt * NN + (size_t)nc * 512) * CC + c0;
  for (int k0 = 0; k0 < 512; k0 += 32) {
    *(s16x8*)&As[r1][kq * 8] =
        *(const s16x8*)(sb + (size_t)r1 * (BT * NN) + k0 + kq * 8);
    if (r2 < KCC)
      *(s16x8*)&As[r2][kq * 8] =
          *(const s16x8*)(sb + (size_t)r2 * (BT * NN) + k0 + kq * 8);
    s16x8 v0 = *(const s16x8*)(xb + (size_t)(k0 + bk) * CC + bc);
    s16x8 v1 = *(const s16x8*)(xb + (size_t)(k0 + bk) * CC + bc + 8);
#pragma unroll
    for (int j = 0; j < 8; ++j) Bs[bc + j][bk] = v0[j];
#pragma unroll
    for (int j = 0; j < 8; ++j) Bs[bc + 8 + j][bk] = v1[j];
    __syncthreads();
    s16x8 af[4], bf[4];
#pragma unroll
    for (int mt = 0; mt < 4; ++mt)
      af[mt] = *(const s16x8*)&As[wm * 64 + mt * 16 + lm][g * 8];
#pragma unroll
    for (int nt = 0; nt < 4; ++nt)
      bf[nt] = *(const s16x8*)&Bs[wn * 64 + nt * 16 + lm][g * 8];
#pragma unroll
    for (int mt = 0; mt < 4; ++mt)
#pragma unroll
      for (int nt = 0; nt < 4; ++nt)
        acc[mt][nt] = __builtin_amdgcn_mfma_f32_16x16x32_bf16(af[mt], bf[nt],
                                                              acc[mt][nt], 0, 0, 0);
    __syncthreads();
  }
  size_t obase = ((size_t)nc * BT + bt) * (KCC * CC);
#pragma unroll
  for (int nt = 0; nt < 4; ++nt) {
    int c = c0 + wn * 64 + nt * 16 + lm;
#pragma unroll
    for (int mt = 0; mt < 4; ++mt) {
#pragma unroll
      for (int rg = 0; rg < 4; ++rg) {
        int m = wm * 64 + mt * 16 + g * 4 + rg;
        if (m < KCC) partial[obase + (size_t)m * CC + c] = acc[mt][nt][rg];
      }
    }
  }
}

// cosine-sim gating + LN -> cin[b][kc][c]; reduces 8 n-chunk partials
__global__ __launch_bounds__(256) void sim_cin(const float* __restrict__ partial,
                                               const float* __restrict__ alpha_p,
                                               const float* __restrict__ beta_p,
                                               const float* __restrict__ lnw,
                                               const float* __restrict__ lnb,
                                               float* __restrict__ cin) {
  int b = blockIdx.x / KCC, kc = blockIdx.x % KCC;
  int c = threadIdx.x;
  float p0 = 0.f, p1 = 0.f, p2 = 0.f, lst = 0.f;
#pragma unroll
  for (int nc = 0; nc < 8; ++nc) {
    size_t base = ((size_t)nc * BT) * KCC * CC;
    p0 += partial[base + ((size_t)(b * 4 + 0) * KCC + kc) * CC + c];
    p1 += partial[base + ((size_t)(b * 4 + 1) * KCC + kc) * CC + c];
    p2 += partial[base + ((size_t)(b * 4 + 2) * KCC + kc) * CC + c];
    lst += partial[base + ((size_t)(b * 4 + 3) * KCC + kc) * CC + c];
  }
  float ll = block_sum256(lst * lst);
  float q0 = block_sum256(p0 * p0);
  float q1 = block_sum256(p1 * p1);
  float q2 = block_sum256(p2 * p2);
  float d0 = block_sum256(lst * p0);
  float d1 = block_sum256(lst * p1);
  float d2 = block_sum256(lst * p2);
  float alpha = alpha_p[0], beta = beta_p[0];
  float nl = sqrtf(ll);
  float c0 = 1.f / (1.f + expf(-(beta + alpha * (d0 / fmaxf(nl * sqrtf(q0), 1e-8f)))));
  float c1 = 1.f / (1.f + expf(-(beta + alpha * (d1 / fmaxf(nl * sqrtf(q1), 1e-8f)))));
  float c2 = 1.f / (1.f + expf(-(beta + alpha * (d2 / fmaxf(nl * sqrtf(q2), 1e-8f)))));
  float v = lst + c0 * p0 + c1 * p1 + c2 * p2;
  float m = block_sum256(v) * (1.f / CC);
  float dv = v - m;
  float var = block_sum256(dv * dv) * (1.f / CC);
  cin[((size_t)b * KCC + kc) * CC + c] = dv * rsqrtf(var + 1e-5f) * lnw[c] + lnb[c];
}

// attention v2: block = (8 query rows, b). K tiled through LDS, V read once.
__global__ __launch_bounds__(256) void attn2(const float* __restrict__ q,
                                             const float* __restrict__ kb,
                                             const float* __restrict__ vb,
                                             bf16_t* __restrict__ ob) {
  int b = blockIdx.y;
  int n0 = blockIdx.x * 8;
  int tid = threadIdx.x;
  __shared__ float qs[8][256];
  __shared__ float Ks[32][257];
  __shared__ float sc[8][8][104];
#pragma unroll
  for (int r = 0; r < 8; ++r)
    qs[r][tid] = q[((size_t)b * NN + n0 + r) * CC + tid] * 0.17677669529663687f;
  int nn = tid >> 5, kcl = tid & 31;
  for (int kt = 0; kt < 4; ++kt) {
    int kbase = kt * 32;
    int rows = (kbase + 32 <= KCC) ? 32 : (KCC - kbase);
    __syncthreads();
    for (int idx = tid; idx < rows * 256; idx += 256) {
      int rr = idx >> 8, cc = idx & 255;
      Ks[rr][cc] = kb[((size_t)b * KCC + kbase + rr) * CC + cc];
    }
    __syncthreads();
    if (kcl < rows) {
#pragma unroll
      for (int h = 0; h < NHH; ++h) {
        float s = 0.f;
#pragma unroll
        for (int d = 0; d < HDD; ++d) s += qs[nn][h * HDD + d] * Ks[kcl][h * HDD + d];
        sc[nn][h][kbase + kcl] = s;
      }
    }
  }
  __syncthreads();
  {
    int tnn = tid >> 5, th = (tid >> 2) & 7, j = tid & 3;
    float mx = -1e30f;
    for (int kc = j * 25; kc < j * 25 + 25; ++kc) mx = fmaxf(mx, sc[tnn][th][kc]);
    mx = fmaxf(mx, __shfl_xor(mx, 1, 64));
    mx = fmaxf(mx, __shfl_xor(mx, 2, 64));
    float sm = 0.f;
    for (int kc = j * 25; kc < j * 25 + 25; ++kc) {
      float e = expf(sc[tnn][th][kc] - mx);
      sc[tnn][th][kc] = e;
      sm += e;
    }
    sm += __shfl_xor(sm, 1, 64);
    sm += __shfl_xor(sm, 2, 64);
    float inv = 1.f / sm;
    for (int kc = j * 25; kc < j * 25 + 25; ++kc) sc[tnn][th][kc] *= inv;
  }
  __syncthreads();
  float o[8] = {0, 0, 0, 0, 0, 0, 0, 0};
  int h = tid >> 5;
  for (int kc = 0; kc < KCC; ++kc) {
    float v = vb[((size_t)b * KCC + kc) * CC + tid];
#pragma unroll
    for (int r = 0; r < 8; ++r) o[r] += sc[r][h][kc] * v;
  }
#pragma unroll
  for (int r = 0; r < 8; ++r)
    ob[((size_t)b * NN + n0 + r) * CC + tid] = f2bf(o[r]);
}

// dst[row][c] = res[row][c] + LN(y[row][:])[c]; WB: also write bf16 copy
template <int WB>
__global__ __launch_bounds__(256) void add_ln(const float* __restrict__ res,
                                              const float* __restrict__ y,
                                              const float* __restrict__ lnw,
                                              const float* __restrict__ lnb,
                                              float* __restrict__ dst,
                                              bf16_t* __restrict__ dst_b) {
  size_t row = blockIdx.x;
  int c = threadIdx.x;
  float v = y[row * CC + c];
  float m = block_sum256(v) * (1.f / CC);
  float dv = v - m;
  float var = block_sum256(dv * dv) * (1.f / CC);
  float o = res[row * CC + c] + dv * rsqrtf(var + 1e-5f) * lnw[c] + lnb[c];
  dst[row * CC + c] = o;
  if (WB) dst_b[row * CC + c] = f2bf(o);
}

// depthwise 3x3 + bias + gelu, all 4 batches (grid 16384)
__global__ __launch_bounds__(256) void dwconv_kernel(const bf16_t* __restrict__ y1,
                                                     const float* __restrict__ dww,
                                                     const float* __restrict__ dwb,
                                                     bf16_t* __restrict__ y2) {
  int b = blockIdx.x >> 12;
  int n = blockIdx.x & 4095;
  int h = n >> 6, w = n & 63;
  int c40 = threadIdx.x * 4;
  float wreg[4][9];
#pragma unroll
  for (int j = 0; j < 4; ++j)
#pragma unroll
    for (int t2 = 0; t2 < 9; ++t2) wreg[j][t2] = dww[(size_t)(c40 + j) * 9 + t2];
  float acc[4] = {0, 0, 0, 0};
#pragma unroll
  for (int dy = 0; dy < 3; ++dy) {
    int r = h + dy - 1;
    if (r < 0 || r >= HH) continue;
#pragma unroll
    for (int dx = 0; dx < 3; ++dx) {
      int cl = w + dx - 1;
      if (cl < 0 || cl >= 64) continue;
      ushort4 u = *(const ushort4*)(y1 + ((size_t)b * NN + r * 64 + cl) * C4 + c40);
      int t2 = dy * 3 + dx;
      acc[0] += bf2f(u.x) * wreg[0][t2];
      acc[1] += bf2f(u.y) * wreg[1][t2];
      acc[2] += bf2f(u.z) * wreg[2][t2];
      acc[3] += bf2f(u.w) * wreg[3][t2];
    }
  }
  ushort4 o;
  o.x = f2bf(gelu_f(acc[0] + dwb[c40 + 0]));
  o.y = f2bf(gelu_f(acc[1] + dwb[c40 + 1]));
  o.z = f2bf(gelu_f(acc[2] + dwb[c40 + 2]));
  o.w = f2bf(gelu_f(acc[3] + dwb[c40 + 3]));
  *(ushort4*)(y2 + ((size_t)b * NN + n) * C4 + c40) = o;
}

extern "C" void kernel_launch(void* const* d_in, const int* in_sizes, int n_in,
                              void* d_out, int out_size, void* d_ws, size_t ws_size,
                              hipStream_t stream) {
  const float* x = (const float*)d_in[0];
  const float* mem = (const float*)d_in[1];
  const float* conv1_w = (const float*)d_in[2];
  const float* conv1_b = (const float*)d_in[3];
  const float* conv2_w = (const float*)d_in[4];
  const float* conv2_b = (const float*)d_in[5];
  const float* conv3_w = (const float*)d_in[6];
  const float* sim_a = (const float*)d_in[7];
  const float* sim_b = (const float*)d_in[8];
  const float* ln_w = (const float*)d_in[9];
  const float* ln_b = (const float*)d_in[10];
  const float* q_w = (const float*)d_in[11];
  const float* q_b = (const float*)d_in[12];
  const float* k_w = (const float*)d_in[13];
  const float* k_b = (const float*)d_in[14];
  const float* v_w = (const float*)d_in[15];
  const float* v_b = (const float*)d_in[16];
  const float* proj_w = (const float*)d_in[17];
  const float* proj_b = (const float*)d_in[18];
  const float* fc1_w = (const float*)d_in[19];
  const float* fc1_b = (const float*)d_in[20];
  const float* dw_w = (const float*)d_in[21];
  const float* dw_b = (const float*)d_in[22];
  const float* fc2_w = (const float*)d_in[23];
  const float* fc2_b = (const float*)d_in[24];

  // Workspace: 101,353,472 B = 96.7 MB (< 104 MB known-good).
  char* base = (char*)d_ws;
  bf16_t* xtb = (bf16_t*)(base);
  bf16_t* by1 = (bf16_t*)(base);
  bf16_t* bh1 = (bf16_t*)(base + 33554432);
  float* qb = (float*)(base + 33554432);
  float* outb = (float*)(base + 33554432);
  float* partial = (float*)(base + 50331648);   // 13.1 MB [center..sim_cin]
  float* pbuf = (float*)(base + 50331648);
  bf16_t* y2 = (bf16_t*)(base + 50331648);      // 33.5 MB [dwconv..fc2]; pbuf/czt dead
  bf16_t* czt = (bf16_t*)(base + 67108864);
  bf16_t* obz = (bf16_t*)(base + 67108864);
  bf16_t* outb_b = (bf16_t*)(base + 67108864);
  bf16_t* wtb = (bf16_t*)(base + 80216064);
  bf16_t* h2c = (bf16_t*)(base + 80216064);
  bf16_t* wbz = (bf16_t*)(base + 96993280);
  float* cin = (float*)(base + 100124672);
  float* kb = (float*)(base + 100534272);
  float* vb = (float*)(base + 100943872);
  float* dout = (float*)d_out;                  // fc2 writes here (yout), add_ln in-place

  bf16_t* conv2_wb = wbz;            // 65536
  bf16_t* conv3_wb = wbz + 65536;    // 25600
  bf16_t* q_wb = wbz + 91136;        // 65536
  bf16_t* proj_wb = wbz + 156672;    // 65536
  bf16_t* fc1_wb = wbz + 222208;     // 262144
  bf16_t* fc2_wb = wbz + 484352;     // 262144

  prologue<<<22436, 256, 0, stream>>>(x, mem, xtb, conv1_w, wtb, conv2_w, conv3_w,
                                      q_w, proj_w, fc1_w, fc2_w, wbz);
  conv1_mfma<<<512, 512, 0, stream>>>(xtb, wtb, conv1_b, bh1);
  for (int i = 0; i < 2; ++i) {
    gemm_mfma<1, 1, 0, 1><<<dim3(2, 256, 1), 256, 0, stream>>>(
        bh1 + (size_t)i * 32768 * CC, conv2_wb, conv2_b, h2c, 32768, 256, 256, 256, 0, 0);
    gemm_mfma<0, 0, 1, 1><<<dim3(1, 256, 1), 256, 0, stream>>>(
        h2c, conv3_wb, nullptr, czt + (size_t)i * 32768, 32768, 100, 256, 65536, 0, 0);
  }
  softmax_rows<<<1600, 256, 0, stream>>>(czt);
  center_mfma<<<dim3(2, 16, 8), 256, 0, stream>>>(czt, xtb, partial);
  sim_cin<<<400, 256, 0, stream>>>(partial, sim_a, sim_b, ln_w, ln_b, cin);
  gemm_mfma<0, 1, 0, 0><<<dim3(2, 32, 4), 256, 0, stream>>>(
      xtb + (size_t)3 * NN * CC, q_wb, q_b, qb, 4096, 256, 256, 256,
      (size_t)4 * NN * CC, (size_t)NN * CC);
  gemm_kv<<<dim3(4, 7, 2), 256, 0, stream>>>(cin, k_w, k_b, v_w, v_b, kb, vb);
  attn2<<<dim3(512, 4), 256, 0, stream>>>(qb, kb, vb, obz);
  gemm_mfma<0, 1, 0, 0><<<dim3(2, 128, 1), 256, 0, stream>>>(obz, proj_wb, proj_b, pbuf,
                                                             16384, 256, 256, 256, 0, 0);
  add_ln<1><<<16384, 256, 0, stream>>>(x, pbuf, ln_w, ln_b, outb, outb_b);
  gemm_mfma<0, 1, 0, 1><<<dim3(8, 128, 1), 256, 0, stream>>>(outb_b, fc1_wb, fc1_b, by1,
                                                             16384, 1024, 256, 1024, 0, 0);
  dwconv_kernel<<<16384, 256, 0, stream>>>(by1, dw_w, dw_b, y2);
  gemm_mfma<0, 1, 0, 0><<<dim3(2, 32, 4), 256, 0, stream>>>(
      y2, fc2_wb, fc2_b, dout, 4096, 256, 1024, 256,
      (size_t)NN * C4, (size_t)NN * CC);
  add_ln<0><<<16384, 256, 0, stream>>>(outb, dout, ln_w, ln_b, dout, nullptr);
}

// Round 5
// 858.641 us; speedup vs baseline: 1.1747x; 1.1747x over previous
//
#include <hip/hip_runtime.h>
#include <math.h>

#define NN 4096
#define CC 256
#define HH 64
#define BT 16
#define KCC 100
#define NHH 8
#define HDD 32
#define C4 1024

typedef unsigned short bf16_t;
typedef short s16x8 __attribute__((ext_vector_type(8)));
typedef float f32x4 __attribute__((ext_vector_type(4)));
typedef float f32x16 __attribute__((ext_vector_type(16)));

__device__ __forceinline__ float bf2f(bf16_t h) {
  return __uint_as_float(((unsigned)h) << 16);
}
__device__ __forceinline__ bf16_t f2bf(float f) {
  unsigned u = __float_as_uint(f);
  return (bf16_t)((u + 0x7FFFu + ((u >> 16) & 1u)) >> 16);
}

__device__ __forceinline__ float gelu_f(float x) {
  return 0.5f * x * (1.0f + erff(x * 0.7071067811865475f));
}

// async global->LDS, 16 B per lane; lds dest = wave-uniform base + lane*16
__device__ __forceinline__ void g2l16(const void* g, void* l) {
  __builtin_amdgcn_global_load_lds((const __attribute__((address_space(1))) void*)g,
                                   (__attribute__((address_space(3))) void*)l, 16, 0, 0);
}

__device__ __forceinline__ float block_sum256(float v) {
  __shared__ float sh[4];
#pragma unroll
  for (int off = 32; off; off >>= 1) v += __shfl_xor(v, off, 64);
  __syncthreads();
  if ((threadIdx.x & 63) == 0) sh[threadIdx.x >> 6] = v;
  __syncthreads();
  return sh[0] + sh[1] + sh[2] + sh[3];
}

__device__ __forceinline__ const float* xt_base(const float* x, const float* mem, int bt) {
  int b = bt >> 2, tt = bt & 3;
  return (tt < 3) ? (mem + (size_t)(b * 3 + tt) * NN * CC)
                  : (x + (size_t)b * NN * CC);
}

// fused prologue: [0,16384) build xtb; [16384,19520) transpose conv1_w -> wtb;
// [19520,22436) convert 6 weight mats to bf16 pack wbz.
__global__ __launch_bounds__(256) void prologue(const float* __restrict__ x,
                                                const float* __restrict__ mem,
                                                bf16_t* __restrict__ xtb,
                                                const float* __restrict__ w1,
                                                bf16_t* __restrict__ wtb,
                                                const float* __restrict__ c2w,
                                                const float* __restrict__ c3w,
                                                const float* __restrict__ qw,
                                                const float* __restrict__ pw,
                                                const float* __restrict__ f1w,
                                                const float* __restrict__ f2w,
                                                bf16_t* __restrict__ wbz) {
  int bid = blockIdx.x;
  int tid = threadIdx.x;
  if (bid < 16384) {
    int i = bid * 256 + tid;
    int c4 = i & 63;
    int n = (i >> 6) & 4095;
    int bt = i >> 18;
    const float* src = xt_base(x, mem, bt) + (size_t)n * CC + c4 * 4;
    float4 v = *(const float4*)src;
    ushort4 o;
    o.x = f2bf(v.x); o.y = f2bf(v.y); o.z = f2bf(v.z); o.w = f2bf(v.w);
    *(ushort4*)(xtb + (size_t)i * 4) = o;
  } else if (bid < 19520) {
    int i = (bid - 16384) * 256 + tid;  // < 802816 exactly
    int cj = i & 7;
    int t = i >> 3;
    int co = t & 63; t >>= 6;
    int oc = t & 3; t >>= 2;
    int kx = t % 7; t /= 7;
    int cq = t & 3; t >>= 2;
    int cg = t & 7;
    int ky = t >> 3;
    int ci = cg * 32 + oc * 8 + cj;
    int cog = cq * 64 + co;
    wtb[i] = f2bf(w1[((size_t)(cog * CC + ci) * 7 + ky) * 7 + kx]);
  } else {
    int j = (bid - 19520) * 256 + tid;  // < 746496 exactly
    float v;
    if (j < 65536) v = c2w[j];
    else if (j < 91136) v = c3w[j - 65536];
    else if (j < 156672) v = qw[j - 91136];
    else if (j < 222208) v = pw[j - 156672];
    else if (j < 484352) v = f1w[j - 222208];
    else v = f2w[j - 484352];
    wbz[j] = f2bf(v);
  }
}

// conv1 v9: occupancy fix. v5-v8 post-mortem: dur == LDS-port-cyc + MFMA-cyc
// (zero overlap) at 2 waves/SIMD in every variant; intra-wave ILP/interleave
// proven unable to overlap the pipes (v7 rotation null, v8 SGB null). m114:
// independent waves DO overlap pipes. So: 1024-thr (16-wave) block, 1/CU,
// 4 waves/SIMD, __launch_bounds__(1024,4) forcing <=128 regs. v7 per-wave
// tile (32x32 MFMA, AI 32: LDS 401K cyc == MFMA 401K cyc, overlap pays max).
// 16-row band: As[22] 98.5KB + Ws dbuf 57.3KB = 155.9KB (launched OK in v5).
__global__ __launch_bounds__(1024, 4) void conv1_mfma(const bf16_t* __restrict__ xtb,
                                                      const bf16_t* __restrict__ wtb,
                                                      const float* __restrict__ bias,
                                                      bf16_t* __restrict__ h1) {
  int bid = blockIdx.x;
  int cq = bid & 3;            // W-slice phase, XCD-aligned
  int rem = bid >> 2;          // 0..63
  int bt = rem & 15;
  int rb = rem >> 4;           // 0..3 : 16-row band
  int r0 = rb * 16;
  int co0 = cq * 64;
  int tid = threadIdx.x;
  int wv = tid >> 6;           // 0..15
  int lane = tid & 63;
  int l31 = lane & 31;
  int h = lane >> 5;           // 0..1 : k-half
  __shared__ __align__(16) short As[22][4][70][8];    // 98,560 B
  __shared__ __align__(16) short Ws[2][7][4][64][8];  // 57,344 B
  {
    s16x8 z = {0, 0, 0, 0, 0, 0, 0, 0};
    for (int i = tid; i < 22 * 4 * 70; i += 1024) *(s16x8*)((short*)As + i * 8) = z;
  }
  __syncthreads();
  f32x16 acc[2][2] = {};       // [mt][nt] 32x32 tiles
  const bf16_t* xb = xtb + (size_t)bt * (NN * CC);
  for (int cig = 0; cig < 8; ++cig) {
    int ci0 = cig * 32;
    // stage As: 22 rows x 4 ci-subgroups (halo rows outside image stay zero)
    for (int t = wv; t < 88; t += 16) {
      int rr = t >> 2, go = t & 3;
      int r = r0 - 3 + rr;
      if (r >= 0 && r < HH) {
        const bf16_t* gsrc = xb + ((size_t)(r * 64 + lane)) * CC + ci0 + go * 8;
        g2l16(gsrc, &As[rr][go][3][0]);
      }
    }
    // stage Ws buf0, ky=0
    {
      const bf16_t* wk = wtb + ((size_t)((0 * 8 + cig) * 4 + cq)) * (1792 * 8);
      for (int t = wv; t < 28; t += 16)
        g2l16(wk + (size_t)t * 512 + lane * 8, (short*)Ws[0] + t * 512);
    }
    __syncthreads();
    for (int ky = 0; ky < 7; ++ky) {
      int cur = ky & 1;
      if (ky < 6) {  // prefetch next ky's W taps into the other buffer
        const bf16_t* wk = wtb + ((size_t)(((ky + 1) * 8 + cig) * 4 + cq)) * (1792 * 8);
        for (int t = wv; t < 28; t += 16)
          g2l16(wk + (size_t)t * 512 + lane * 8, (short*)Ws[cur ^ 1] + t * 512);
      }
#pragma unroll
      for (int kx = 0; kx < 7; ++kx) {
        s16x8 fa[2][2], fb[2][2];  // [mt|nt][ks]
#pragma unroll
        for (int mt = 0; mt < 2; ++mt)
#pragma unroll
          for (int ks = 0; ks < 2; ++ks) {
            fa[mt][ks] = *(const s16x8*)&As[wv + ky][ks * 2 + h][mt * 32 + l31 + kx][0];
            fb[mt][ks] = *(const s16x8*)&Ws[cur][kx][ks * 2 + h][mt * 32 + l31][0];
          }
#pragma unroll
        for (int ks = 0; ks < 2; ++ks)
#pragma unroll
          for (int mt = 0; mt < 2; ++mt)
#pragma unroll
            for (int nt = 0; nt < 2; ++nt)
              acc[mt][nt] = __builtin_amdgcn_mfma_f32_32x32x16_bf16(
                  fa[mt][ks], fb[nt][ks], acc[mt][nt], 0, 0, 0);
      }
      __syncthreads();  // drains vmcnt: next Ws buffer ready; readers done
    }
  }
  int row = r0 + wv;
  const size_t xbase = (size_t)bt * (NN * CC);
#pragma unroll
  for (int nt = 0; nt < 2; ++nt) {
    int co = co0 + nt * 32 + l31;
    float bs = bias[co];
#pragma unroll
    for (int mt = 0; mt < 2; ++mt) {
#pragma unroll
      for (int rg = 0; rg < 16; ++rg) {
        int px = mt * 32 + (rg & 3) + 8 * (rg >> 2) + 4 * h;
        float vv = acc[mt][nt][rg] + bs;
        h1[xbase + (size_t)(row * 64 + px) * CC + co] = f2bf(gelu_f(vv));
      }
    }
  }
}

// bf16 MFMA GEMM with optional z-slab batching (unchanged)
template <int GELU, int BIAS, int TOUT, int OBF>
__global__ __launch_bounds__(256) void gemm_mfma(const bf16_t* __restrict__ A,
                                                 const bf16_t* __restrict__ W,
                                                 const float* __restrict__ bias,
                                                 void* __restrict__ outp,
                                                 int M, int N, int K, int ldo,
                                                 size_t aStr, size_t oStr) {
  __shared__ short As[128][40];
  __shared__ short Bs[128][40];
  A += (size_t)blockIdx.z * aStr;
  size_t obase = (size_t)blockIdx.z * oStr;
  int tid = threadIdx.x;
  int n0 = blockIdx.x * 128, m0 = blockIdx.y * 128;
  int lane = tid & 63, wv = tid >> 6;
  int wm = wv & 1, wn = wv >> 1;
  int lm = lane & 15, g = lane >> 4;
  f32x4 acc[4][4] = {};
  int r1 = tid >> 2, kq = tid & 3;
  int r2 = r1 + 64;
  for (int k0 = 0; k0 < K; k0 += 32) {
    *(s16x8*)&As[r1][kq * 8] = *(const s16x8*)(A + (size_t)(m0 + r1) * K + k0 + kq * 8);
    *(s16x8*)&As[r2][kq * 8] = *(const s16x8*)(A + (size_t)(m0 + r2) * K + k0 + kq * 8);
    s16x8 z = {0, 0, 0, 0, 0, 0, 0, 0};
    s16x8 b1 = z, b2 = z;
    if (n0 + r1 < N) b1 = *(const s16x8*)(W + (size_t)(n0 + r1) * K + k0 + kq * 8);
    if (n0 + r2 < N) b2 = *(const s16x8*)(W + (size_t)(n0 + r2) * K + k0 + kq * 8);
    *(s16x8*)&Bs[r1][kq * 8] = b1;
    *(s16x8*)&Bs[r2][kq * 8] = b2;
    __syncthreads();
    s16x8 af[4], bf[4];
#pragma unroll
    for (int mt = 0; mt < 4; ++mt)
      af[mt] = *(const s16x8*)&As[wm * 64 + mt * 16 + lm][g * 8];
#pragma unroll
    for (int nt = 0; nt < 4; ++nt)
      bf[nt] = *(const s16x8*)&Bs[wn * 64 + nt * 16 + lm][g * 8];
#pragma unroll
    for (int mt = 0; mt < 4; ++mt)
#pragma unroll
      for (int nt = 0; nt < 4; ++nt)
        acc[mt][nt] = __builtin_amdgcn_mfma_f32_16x16x32_bf16(af[mt], bf[nt],
                                                              acc[mt][nt], 0, 0, 0);
    __syncthreads();
  }
#pragma unroll
  for (int nt = 0; nt < 4; ++nt) {
    int n = n0 + wn * 64 + nt * 16 + lm;
    if (n >= N) continue;
    float bs = BIAS ? bias[n] : 0.f;
#pragma unroll
    for (int mt = 0; mt < 4; ++mt) {
#pragma unroll
      for (int rg = 0; rg < 4; ++rg) {
        int m = m0 + wm * 64 + mt * 16 + g * 4 + rg;
        float v = acc[mt][nt][rg] + bs;
        if (GELU) v = gelu_f(v);
        size_t idx = obase + (TOUT ? ((size_t)n * ldo + m) : ((size_t)m * ldo + n));
        if (OBF)
          ((bf16_t*)outp)[idx] = f2bf(v);
        else
          ((float*)outp)[idx] = v;
      }
    }
  }
}

// fused k/v projections: z=0 -> k, z=1 -> v. M=400, N=256, K=256.
__global__ __launch_bounds__(256) void gemm_kv(const float* __restrict__ cin,
                                               const float* __restrict__ kw,
                                               const float* __restrict__ kbias,
                                               const float* __restrict__ vw,
                                               const float* __restrict__ vbias,
                                               float* __restrict__ kout,
                                               float* __restrict__ vout) {
  const float* Wm = blockIdx.z ? vw : kw;
  const float* bias = blockIdx.z ? vbias : kbias;
  float* outp = blockIdx.z ? vout : kout;
  const int M = 400, N = 256, K = 256;
  __shared__ float As[16][68];
  __shared__ float Ws[16][68];
  int tid = threadIdx.x;
  int n0 = blockIdx.x * 64, m0 = blockIdx.y * 64;
  int txn = tid & 15, tym = tid >> 4;
  int mi = tid >> 2, kq = (tid & 3) * 4;
  float acc[4][4] = {};
  for (int k0 = 0; k0 < K; k0 += 16) {
    float4 av = {0, 0, 0, 0}, wvv = {0, 0, 0, 0};
    if (m0 + mi < M) av = *(const float4*)&cin[(size_t)(m0 + mi) * K + k0 + kq];
    if (n0 + mi < N) wvv = *(const float4*)&Wm[(size_t)(n0 + mi) * K + k0 + kq];
    As[kq + 0][mi] = av.x; As[kq + 1][mi] = av.y; As[kq + 2][mi] = av.z; As[kq + 3][mi] = av.w;
    Ws[kq + 0][mi] = wvv.x; Ws[kq + 1][mi] = wvv.y; Ws[kq + 2][mi] = wvv.z; Ws[kq + 3][mi] = wvv.w;
    __syncthreads();
#pragma unroll
    for (int ki = 0; ki < 16; ++ki) {
      float4 a4 = *(const float4*)&As[ki][tym * 4];
      float4 w4 = *(const float4*)&Ws[ki][txn * 4];
      float am[4] = {a4.x, a4.y, a4.z, a4.w};
      float wn[4] = {w4.x, w4.y, w4.z, w4.w};
#pragma unroll
      for (int i = 0; i < 4; ++i)
#pragma unroll
        for (int j = 0; j < 4; ++j) acc[i][j] += am[i] * wn[j];
    }
    __syncthreads();
  }
#pragma unroll
  for (int i = 0; i < 4; ++i) {
    int m = m0 + tym * 4 + i;
    if (m >= M) continue;
#pragma unroll
    for (int j = 0; j < 4; ++j) {
      int n = n0 + txn * 4 + j;
      outp[(size_t)m * 256 + n] = acc[i][j] + bias[n];
    }
  }
}

// 1600 rows of 4096 bf16, softmax in place; thread owns 16 contiguous elems
__global__ __launch_bounds__(256) void softmax_rows(bf16_t* __restrict__ p) {
  __shared__ float sh[8];
  int tid = threadIdx.x;
  bf16_t* base = p + (size_t)blockIdx.x * NN + tid * 16;
  s16x8 a = *(const s16x8*)base;
  s16x8 b = *(const s16x8*)(base + 8);
  float vals[16];
#pragma unroll
  for (int j = 0; j < 8; ++j) {
    vals[j] = bf2f((bf16_t)a[j]);
    vals[8 + j] = bf2f((bf16_t)b[j]);
  }
  float mx = -1e30f;
#pragma unroll
  for (int j = 0; j < 16; ++j) mx = fmaxf(mx, vals[j]);
#pragma unroll
  for (int off = 32; off; off >>= 1) mx = fmaxf(mx, __shfl_xor(mx, off, 64));
  if ((tid & 63) == 0) sh[tid >> 6] = mx;
  __syncthreads();
  mx = fmaxf(fmaxf(sh[0], sh[1]), fmaxf(sh[2], sh[3]));
  float s = 0.f;
#pragma unroll
  for (int j = 0; j < 16; ++j) {
    vals[j] = expf(vals[j] - mx);
    s += vals[j];
  }
#pragma unroll
  for (int off = 32; off; off >>= 1) s += __shfl_xor(s, off, 64);
  if ((tid & 63) == 0) sh[4 + (tid >> 6)] = s;
  __syncthreads();
  s = sh[4] + sh[5] + sh[6] + sh[7];
  float inv = 1.f / s;
  s16x8 oa, ob;
#pragma unroll
  for (int j = 0; j < 8; ++j) {
    oa[j] = (short)f2bf(vals[j] * inv);
    ob[j] = (short)f2bf(vals[8 + j] * inv);
  }
  *(s16x8*)base = oa;
  *(s16x8*)(base + 8) = ob;
}

// center via MFMA split-K (8 chunks of 512): partial[nc][bt][kc][c].
__global__ __launch_bounds__(256) void center_mfma(const bf16_t* __restrict__ soft,
                                                   const bf16_t* __restrict__ xtb,
                                                   float* __restrict__ partial) {
  int c0 = blockIdx.x * 128;
  int bt = blockIdx.y;
  int nc = blockIdx.z;
  int tid = threadIdx.x;
  int lane = tid & 63, wv = tid >> 6;
  int wm = wv & 1, wn = wv >> 1;
  int lm = lane & 15, g = lane >> 4;
  __shared__ short As[128][40];
  __shared__ short Bs[128][40];
  f32x4 acc[4][4] = {};
  int r1 = tid >> 2, kq = tid & 3;
  int r2 = r1 + 64;
  int bk = tid & 31, bc = (tid >> 5) * 16;
  const bf16_t* sb = soft + (size_t)bt * NN + (size_t)nc * 512;
  const bf16_t* xb = xtb + ((size_t)bt * NN + (size_t)nc * 512) * CC + c0;
  for (int k0 = 0; k0 < 512; k0 += 32) {
    *(s16x8*)&As[r1][kq * 8] =
        *(const s16x8*)(sb + (size_t)r1 * (BT * NN) + k0 + kq * 8);
    if (r2 < KCC)
      *(s16x8*)&As[r2][kq * 8] =
          *(const s16x8*)(sb + (size_t)r2 * (BT * NN) + k0 + kq * 8);
    s16x8 v0 = *(const s16x8*)(xb + (size_t)(k0 + bk) * CC + bc);
    s16x8 v1 = *(const s16x8*)(xb + (size_t)(k0 + bk) * CC + bc + 8);
#pragma unroll
    for (int j = 0; j < 8; ++j) Bs[bc + j][bk] = v0[j];
#pragma unroll
    for (int j = 0; j < 8; ++j) Bs[bc + 8 + j][bk] = v1[j];
    __syncthreads();
    s16x8 af[4], bf[4];
#pragma unroll
    for (int mt = 0; mt < 4; ++mt)
      af[mt] = *(const s16x8*)&As[wm * 64 + mt * 16 + lm][g * 8];
#pragma unroll
    for (int nt = 0; nt < 4; ++nt)
      bf[nt] = *(const s16x8*)&Bs[wn * 64 + nt * 16 + lm][g * 8];
#pragma unroll
    for (int mt = 0; mt < 4; ++mt)
#pragma unroll
      for (int nt = 0; nt < 4; ++nt)
        acc[mt][nt] = __builtin_amdgcn_mfma_f32_16x16x32_bf16(af[mt], bf[nt],
                                                              acc[mt][nt], 0, 0, 0);
    __syncthreads();
  }
  size_t obase = ((size_t)nc * BT + bt) * (KCC * CC);
#pragma unroll
  for (int nt = 0; nt < 4; ++nt) {
    int c = c0 + wn * 64 + nt * 16 + lm;
#pragma unroll
    for (int mt = 0; mt < 4; ++mt) {
#pragma unroll
      for (int rg = 0; rg < 4; ++rg) {
        int m = wm * 64 + mt * 16 + g * 4 + rg;
        if (m < KCC) partial[obase + (size_t)m * CC + c] = acc[mt][nt][rg];
      }
    }
  }
}

// cosine-sim gating + LN -> cin[b][kc][c]; reduces 8 n-chunk partials
__global__ __launch_bounds__(256) void sim_cin(const float* __restrict__ partial,
                                               const float* __restrict__ alpha_p,
                                               const float* __restrict__ beta_p,
                                               const float* __restrict__ lnw,
                                               const float* __restrict__ lnb,
                                               float* __restrict__ cin) {
  int b = blockIdx.x / KCC, kc = blockIdx.x % KCC;
  int c = threadIdx.x;
  float p0 = 0.f, p1 = 0.f, p2 = 0.f, lst = 0.f;
#pragma unroll
  for (int nc = 0; nc < 8; ++nc) {
    size_t base = ((size_t)nc * BT) * KCC * CC;
    p0 += partial[base + ((size_t)(b * 4 + 0) * KCC + kc) * CC + c];
    p1 += partial[base + ((size_t)(b * 4 + 1) * KCC + kc) * CC + c];
    p2 += partial[base + ((size_t)(b * 4 + 2) * KCC + kc) * CC + c];
    lst += partial[base + ((size_t)(b * 4 + 3) * KCC + kc) * CC + c];
  }
  float ll = block_sum256(lst * lst);
  float q0 = block_sum256(p0 * p0);
  float q1 = block_sum256(p1 * p1);
  float q2 = block_sum256(p2 * p2);
  float d0 = block_sum256(lst * p0);
  float d1 = block_sum256(lst * p1);
  float d2 = block_sum256(lst * p2);
  float alpha = alpha_p[0], beta = beta_p[0];
  float nl = sqrtf(ll);
  float c0 = 1.f / (1.f + expf(-(beta + alpha * (d0 / fmaxf(nl * sqrtf(q0), 1e-8f)))));
  float c1 = 1.f / (1.f + expf(-(beta + alpha * (d1 / fmaxf(nl * sqrtf(q1), 1e-8f)))));
  float c2 = 1.f / (1.f + expf(-(beta + alpha * (d2 / fmaxf(nl * sqrtf(q2), 1e-8f)))));
  float v = lst + c0 * p0 + c1 * p1 + c2 * p2;
  float m = block_sum256(v) * (1.f / CC);
  float dv = v - m;
  float var = block_sum256(dv * dv) * (1.f / CC);
  cin[((size_t)b * KCC + kc) * CC + c] = dv * rsqrtf(var + 1e-5f) * lnw[c] + lnb[c];
}

// attention v2: block = (8 query rows, b). K tiled through LDS, V read once.
__global__ __launch_bounds__(256) void attn2(const float* __restrict__ q,
                                             const float* __restrict__ kb,
                                             const float* __restrict__ vb,
                                             bf16_t* __restrict__ ob) {
  int b = blockIdx.y;
  int n0 = blockIdx.x * 8;
  int tid = threadIdx.x;
  __shared__ float qs[8][256];
  __shared__ float Ks[32][257];
  __shared__ float sc[8][8][104];
#pragma unroll
  for (int r = 0; r < 8; ++r)
    qs[r][tid] = q[((size_t)b * NN + n0 + r) * CC + tid] * 0.17677669529663687f;
  int nn = tid >> 5, kcl = tid & 31;
  for (int kt = 0; kt < 4; ++kt) {
    int kbase = kt * 32;
    int rows = (kbase + 32 <= KCC) ? 32 : (KCC - kbase);
    __syncthreads();
    for (int idx = tid; idx < rows * 256; idx += 256) {
      int rr = idx >> 8, cc = idx & 255;
      Ks[rr][cc] = kb[((size_t)b * KCC + kbase + rr) * CC + cc];
    }
    __syncthreads();
    if (kcl < rows) {
#pragma unroll
      for (int h = 0; h < NHH; ++h) {
        float s = 0.f;
#pragma unroll
        for (int d = 0; d < HDD; ++d) s += qs[nn][h * HDD + d] * Ks[kcl][h * HDD + d];
        sc[nn][h][kbase + kcl] = s;
      }
    }
  }
  __syncthreads();
  {
    int tnn = tid >> 5, th = (tid >> 2) & 7, j = tid & 3;
    float mx = -1e30f;
    for (int kc = j * 25; kc < j * 25 + 25; ++kc) mx = fmaxf(mx, sc[tnn][th][kc]);
    mx = fmaxf(mx, __shfl_xor(mx, 1, 64));
    mx = fmaxf(mx, __shfl_xor(mx, 2, 64));
    float sm = 0.f;
    for (int kc = j * 25; kc < j * 25 + 25; ++kc) {
      float e = expf(sc[tnn][th][kc] - mx);
      sc[tnn][th][kc] = e;
      sm += e;
    }
    sm += __shfl_xor(sm, 1, 64);
    sm += __shfl_xor(sm, 2, 64);
    float inv = 1.f / sm;
    for (int kc = j * 25; kc < j * 25 + 25; ++kc) sc[tnn][th][kc] *= inv;
  }
  __syncthreads();
  float o[8] = {0, 0, 0, 0, 0, 0, 0, 0};
  int h = tid >> 5;
  for (int kc = 0; kc < KCC; ++kc) {
    float v = vb[((size_t)b * KCC + kc) * CC + tid];
#pragma unroll
    for (int r = 0; r < 8; ++r) o[r] += sc[r][h][kc] * v;
  }
#pragma unroll
  for (int r = 0; r < 8; ++r)
    ob[((size_t)b * NN + n0 + r) * CC + tid] = f2bf(o[r]);
}

// dst[row][c] = res[row][c] + LN(y[row][:])[c]; WB: also write bf16 copy
template <int WB>
__global__ __launch_bounds__(256) void add_ln(const float* __restrict__ res,
                                              const float* __restrict__ y,
                                              const float* __restrict__ lnw,
                                              const float* __restrict__ lnb,
                                              float* __restrict__ dst,
                                              bf16_t* __restrict__ dst_b) {
  size_t row = blockIdx.x;
  int c = threadIdx.x;
  float v = y[row * CC + c];
  float m = block_sum256(v) * (1.f / CC);
  float dv = v - m;
  float var = block_sum256(dv * dv) * (1.f / CC);
  float o = res[row * CC + c] + dv * rsqrtf(var + 1e-5f) * lnw[c] + lnb[c];
  dst[row * CC + c] = o;
  if (WB) dst_b[row * CC + c] = f2bf(o);
}

// depthwise 3x3 + bias + gelu, all 4 batches (grid 16384)
__global__ __launch_bounds__(256) void dwconv_kernel(const bf16_t* __restrict__ y1,
                                                     const float* __restrict__ dww,
                                                     const float* __restrict__ dwb,
                                                     bf16_t* __restrict__ y2) {
  int b = blockIdx.x >> 12;
  int n = blockIdx.x & 4095;
  int h = n >> 6, w = n & 63;
  int c40 = threadIdx.x * 4;
  float wreg[4][9];
#pragma unroll
  for (int j = 0; j < 4; ++j)
#pragma unroll
    for (int t2 = 0; t2 < 9; ++t2) wreg[j][t2] = dww[(size_t)(c40 + j) * 9 + t2];
  float acc[4] = {0, 0, 0, 0};
#pragma unroll
  for (int dy = 0; dy < 3; ++dy) {
    int r = h + dy - 1;
    if (r < 0 || r >= HH) continue;
#pragma unroll
    for (int dx = 0; dx < 3; ++dx) {
      int cl = w + dx - 1;
      if (cl < 0 || cl >= 64) continue;
      ushort4 u = *(const ushort4*)(y1 + ((size_t)b * NN + r * 64 + cl) * C4 + c40);
      int t2 = dy * 3 + dx;
      acc[0] += bf2f(u.x) * wreg[0][t2];
      acc[1] += bf2f(u.y) * wreg[1][t2];
      acc[2] += bf2f(u.z) * wreg[2][t2];
      acc[3] += bf2f(u.w) * wreg[3][t2];
    }
  }
  ushort4 o;
  o.x = f2bf(gelu_f(acc[0] + dwb[c40 + 0]));
  o.y = f2bf(gelu_f(acc[1] + dwb[c40 + 1]));
  o.z = f2bf(gelu_f(acc[2] + dwb[c40 + 2]));
  o.w = f2bf(gelu_f(acc[3] + dwb[c40 + 3]));
  *(ushort4*)(y2 + ((size_t)b * NN + n) * C4 + c40) = o;
}

extern "C" void kernel_launch(void* const* d_in, const int* in_sizes, int n_in,
                              void* d_out, int out_size, void* d_ws, size_t ws_size,
                              hipStream_t stream) {
  const float* x = (const float*)d_in[0];
  const float* mem = (const float*)d_in[1];
  const float* conv1_w = (const float*)d_in[2];
  const float* conv1_b = (const float*)d_in[3];
  const float* conv2_w = (const float*)d_in[4];
  const float* conv2_b = (const float*)d_in[5];
  const float* conv3_w = (const float*)d_in[6];
  const float* sim_a = (const float*)d_in[7];
  const float* sim_b = (const float*)d_in[8];
  const float* ln_w = (const float*)d_in[9];
  const float* ln_b = (const float*)d_in[10];
  const float* q_w = (const float*)d_in[11];
  const float* q_b = (const float*)d_in[12];
  const float* k_w = (const float*)d_in[13];
  const float* k_b = (const float*)d_in[14];
  const float* v_w = (const float*)d_in[15];
  const float* v_b = (const float*)d_in[16];
  const float* proj_w = (const float*)d_in[17];
  const float* proj_b = (const float*)d_in[18];
  const float* fc1_w = (const float*)d_in[19];
  const float* fc1_b = (const float*)d_in[20];
  const float* dw_w = (const float*)d_in[21];
  const float* dw_b = (const float*)d_in[22];
  const float* fc2_w = (const float*)d_in[23];
  const float* fc2_b = (const float*)d_in[24];

  // Workspace: 101,353,472 B = 96.7 MB (< 104 MB known-good).
  char* base = (char*)d_ws;
  bf16_t* xtb = (bf16_t*)(base);
  bf16_t* by1 = (bf16_t*)(base);
  bf16_t* bh1 = (bf16_t*)(base + 33554432);
  float* qb = (float*)(base + 33554432);
  float* outb = (float*)(base + 33554432);
  float* partial = (float*)(base + 50331648);   // 13.1 MB [center..sim_cin]
  float* pbuf = (float*)(base + 50331648);
  bf16_t* y2 = (bf16_t*)(base + 50331648);      // 33.5 MB [dwconv..fc2]; pbuf/czt dead
  bf16_t* czt = (bf16_t*)(base + 67108864);
  bf16_t* obz = (bf16_t*)(base + 67108864);
  bf16_t* outb_b = (bf16_t*)(base + 67108864);
  bf16_t* wtb = (bf16_t*)(base + 80216064);
  bf16_t* h2c = (bf16_t*)(base + 80216064);
  bf16_t* wbz = (bf16_t*)(base + 96993280);
  float* cin = (float*)(base + 100124672);
  float* kb = (float*)(base + 100534272);
  float* vb = (float*)(base + 100943872);
  float* dout = (float*)d_out;                  // fc2 writes here (yout), add_ln in-place

  bf16_t* conv2_wb = wbz;            // 65536
  bf16_t* conv3_wb = wbz + 65536;    // 25600
  bf16_t* q_wb = wbz + 91136;        // 65536
  bf16_t* proj_wb = wbz + 156672;    // 65536
  bf16_t* fc1_wb = wbz + 222208;     // 262144
  bf16_t* fc2_wb = wbz + 484352;     // 262144

  prologue<<<22436, 256, 0, stream>>>(x, mem, xtb, conv1_w, wtb, conv2_w, conv3_w,
                                      q_w, proj_w, fc1_w, fc2_w, wbz);
  conv1_mfma<<<256, 1024, 0, stream>>>(xtb, wtb, conv1_b, bh1);
  for (int i = 0; i < 2; ++i) {
    gemm_mfma<1, 1, 0, 1><<<dim3(2, 256, 1), 256, 0, stream>>>(
        bh1 + (size_t)i * 32768 * CC, conv2_wb, conv2_b, h2c, 32768, 256, 256, 256, 0, 0);
    gemm_mfma<0, 0, 1, 1><<<dim3(1, 256, 1), 256, 0, stream>>>(
        h2c, conv3_wb, nullptr, czt + (size_t)i * 32768, 32768, 100, 256, 65536, 0, 0);
  }
  softmax_rows<<<1600, 256, 0, stream>>>(czt);
  center_mfma<<<dim3(2, 16, 8), 256, 0, stream>>>(czt, xtb, partial);
  sim_cin<<<400, 256, 0, stream>>>(partial, sim_a, sim_b, ln_w, ln_b, cin);
  gemm_mfma<0, 1, 0, 0><<<dim3(2, 32, 4), 256, 0, stream>>>(
      xtb + (size_t)3 * NN * CC, q_wb, q_b, qb, 4096, 256, 256, 256,
      (size_t)4 * NN * CC, (size_t)NN * CC);
  gemm_kv<<<dim3(4, 7, 2), 256, 0, stream>>>(cin, k_w, k_b, v_w, v_b, kb, vb);
  attn2<<<dim3(512, 4), 256, 0, stream>>>(qb, kb, vb, obz);
  gemm_mfma<0, 1, 0, 0><<<dim3(2, 128, 1), 256, 0, stream>>>(obz, proj_wb, proj_b, pbuf,
                                                             16384, 256, 256, 256, 0, 0);
  add_ln<1><<<16384, 256, 0, stream>>>(x, pbuf, ln_w, ln_b, outb, outb_b);
  gemm_mfma<0, 1, 0, 1><<<dim3(8, 128, 1), 256, 0, stream>>>(outb_b, fc1_wb, fc1_b, by1,
                                                             16384, 1024, 256, 1024, 0, 0);
  dwconv_kernel<<<16384, 256, 0, stream>>>(by1, dw_w, dw_b, y2);
  gemm_mfma<0, 1, 0, 0><<<dim3(2, 32, 4), 256, 0, stream>>>(
      y2, fc2_wb, fc2_b, dout, 4096, 256, 1024, 256,
      (size_t)NN * C4, (size_t)NN * CC);
  add_ln<0><<<16384, 256, 0, stream>>>(outb, dout, ln_w, ln_b, dout, nullptr);
}